// Round 6
// baseline (229.688 us; speedup 1.0000x reference)
//
#include <hip/hip_runtime.h>

// Problem constants: B=8, T=2048, C=1024, H=128
constexpr int kB = 8;
constexpr int kT = 2048;
constexpr int kC = 1024;
constexpr int kH = 128;
constexpr int kM = kB * kT;                 // 16384 rows
constexpr size_t kMH = (size_t)kM * kH;     // 2,097,152
constexpr size_t kWH = (size_t)kC * kH;     // 131,072

// q is pre-scaled by sqrt(C)*log2(e) so softmax can use exp2 directly.
#define QSCALE 46.166241308446828f          // 32 * 1.4426950408889634

typedef __attribute__((ext_vector_type(8))) short bf16x8;   // MFMA A/B frag
typedef __attribute__((ext_vector_type(4))) float f32x4;    // MFMA C/D frag

// ws layout (ushort): qhi | qlo | khi | klo | vT[B][H][T] | 6x WT (hi/lo per mat)

__device__ inline unsigned short f2bf_rne(float f) {
    union { float f; unsigned int u; } x; x.f = f;
    unsigned int r = x.u + 0x7fff + ((x.u >> 16) & 1);
    return (unsigned short)(r >> 16);
}
__device__ inline float bf2f(unsigned short h) {
    union { float f; unsigned int u; } x; x.u = ((unsigned int)h) << 16;
    return x.f;
}
__device__ inline unsigned int pack_hi2(float a, float b) {  // trunc-hi16 pack
    return __builtin_amdgcn_perm(__float_as_uint(b), __float_as_uint(a),
                                 0x07060302u);
}
__device__ inline float hi_part(float v) {
    return __uint_as_float(__float_as_uint(v) & 0xffff0000u);
}
__device__ inline void load_lds16(const unsigned short* g, unsigned short* l) {
    __builtin_amdgcn_global_load_lds(
        (const __attribute__((address_space(1))) unsigned int*)g,
        (__attribute__((address_space(3))) unsigned int*)l, 16, 0, 0);
}

// ---------------------------------------------------------------------------
// Kernel 0: split + transpose weights -> WT_hi (RNE) / WT_lo [H][C] bf16.
// ---------------------------------------------------------------------------
__global__ __launch_bounds__(256) void prep_w(
    const float* __restrict__ Wk, const float* __restrict__ Wq,
    const float* __restrict__ Wv, unsigned short* __restrict__ ws)
{
    const int h = blockIdx.x;
    const int mat = blockIdx.y;
    const float* W = (mat == 0) ? Wq : (mat == 1) ? Wk : Wv;
    unsigned short* hi = ws + 5 * kMH + (size_t)(mat * 2) * kWH;
    unsigned short* lo = hi + kWH;

    const int k0 = threadIdx.x * 4;
    unsigned short hv[4], lv[4];
#pragma unroll
    for (int j = 0; j < 4; ++j) {
        const float f = W[(size_t)(k0 + j) * kH + h];
        hv[j] = f2bf_rne(f);
        lv[j] = f2bf_rne(f - bf2f(hv[j]));
    }
    *(uint2*)&hi[(size_t)h * kC + k0] =
        make_uint2(((unsigned)hv[1] << 16) | hv[0], ((unsigned)hv[3] << 16) | hv[2]);
    *(uint2*)&lo[(size_t)h * kC + k0] =
        make_uint2(((unsigned)lv[1] << 16) | lv[0], ((unsigned)lv[3] << 16) | lv[2]);
}

// ---------------------------------------------------------------------------
// Kernel 1: QKV projection. 768 blocks, M=64, K-step 64 (half the barriers
// vs K-step 32):
//   idx<256: q (split-bf16)   256..511: k (split-bf16)   >=512: v (single RNE)
// 3 blocks/CU (51 KB LDS). B tiles via global_load_lds (swizzled).
// ---------------------------------------------------------------------------
__global__ __launch_bounds__(256) void qkv_mfma(
    const float* __restrict__ x, unsigned short* __restrict__ ws)
{
    __shared__ __align__(16) unsigned short Ah[64][72];
    __shared__ __align__(16) unsigned short Al[64][72];
    __shared__ __align__(16) unsigned short Bh[128 * 64];
    __shared__ __align__(16) unsigned short Bl[128 * 64];

    const int idx = blockIdx.x;
    const int mat = idx >> 8;               // 0=q, 1=k, 2=v
    const int m0 = (idx & 255) * 64;
    const unsigned short* wThi = ws + 5 * kMH + (size_t)(mat * 2) * kWH;
    const unsigned short* wTlo = wThi + kWH;

    const int tid = threadIdx.x;
    const int w = tid >> 6, lane = tid & 63;
    const int li = lane & 15, quad = lane >> 4;
    const int wm = w >> 1, wn = w & 1;      // row-32-half, col-64-half

    const int ar = tid >> 2;                // A-stage row 0..63
    const int ac = (tid & 3) * 16;          // A-stage col (4 float4)

    f32x4 acc[2][4];
#pragma unroll
    for (int i = 0; i < 2; ++i)
#pragma unroll
        for (int j = 0; j < 4; ++j) acc[i][j] = (f32x4){0.f, 0.f, 0.f, 0.f};

    if (mat <= 1) {
        // -------- q / k : split-bf16 (3 MFMAs per product) --------
        for (int kt = 0; kt < kC; kt += 64) {
            if (kt) __syncthreads();
            // A: x[64][64] fp32 -> trunc hi/lo bf16
#pragma unroll
            for (int u = 0; u < 4; ++u) {
                const float4 xv =
                    *(const float4*)(x + (size_t)(m0 + ar) * kC + kt + ac + u * 4);
                const float l0 = xv.x - hi_part(xv.x), l1 = xv.y - hi_part(xv.y);
                const float l2 = xv.z - hi_part(xv.z), l3 = xv.w - hi_part(xv.w);
                *(uint2*)&Ah[ar][ac + u * 4] =
                    make_uint2(pack_hi2(xv.x, xv.y), pack_hi2(xv.z, xv.w));
                *(uint2*)&Al[ar][ac + u * 4] =
                    make_uint2(pack_hi2(l0, l1), pack_hi2(l2, l3));
            }
            // B: DMA [128][64] hi+lo; granule p of row r holds global p^(r&7)
#pragma unroll
            for (int u = 0; u < 4; ++u) {
                const int f = u * 256 + tid;
                const int row = f >> 3, g = (f & 7) ^ (row & 7);
                load_lds16(wThi + (size_t)row * kC + kt + g * 8, Bh + f * 8);
                load_lds16(wTlo + (size_t)row * kC + kt + g * 8, Bl + f * 8);
            }
            __syncthreads();

#pragma unroll
            for (int kc = 0; kc < 2; ++kc) {
                bf16x8 ah[2], al[2];
#pragma unroll
                for (int mt = 0; mt < 2; ++mt) {
                    ah[mt] = *(const bf16x8*)&Ah[wm * 32 + mt * 16 + li][kc * 32 + quad * 8];
                    al[mt] = *(const bf16x8*)&Al[wm * 32 + mt * 16 + li][kc * 32 + quad * 8];
                }
#pragma unroll
                for (int nt = 0; nt < 4; ++nt) {
                    const int row = wn * 64 + nt * 16 + li;
                    const int pos = (kc * 4 + quad) ^ (row & 7);
                    const bf16x8 bh = *(const bf16x8*)&Bh[row * 64 + pos * 8];
                    const bf16x8 bl = *(const bf16x8*)&Bl[row * 64 + pos * 8];
#pragma unroll
                    for (int mt = 0; mt < 2; ++mt) {
                        acc[mt][nt] = __builtin_amdgcn_mfma_f32_16x16x32_bf16(ah[mt], bh, acc[mt][nt], 0, 0, 0);
                        acc[mt][nt] = __builtin_amdgcn_mfma_f32_16x16x32_bf16(al[mt], bh, acc[mt][nt], 0, 0, 0);
                        acc[mt][nt] = __builtin_amdgcn_mfma_f32_16x16x32_bf16(ah[mt], bl, acc[mt][nt], 0, 0, 0);
                    }
                }
            }
        }
        // epilogue: hi/lo split [M][H] (q scaled by 32*log2e for exp2 softmax)
        unsigned short* hip_ = ws + (size_t)(mat * 2) * kMH;
        unsigned short* lop  = hip_ + kMH;
        const float sc = (mat == 0) ? QSCALE : 1.0f;
#pragma unroll
        for (int mt = 0; mt < 2; ++mt)
#pragma unroll
            for (int nt = 0; nt < 4; ++nt) {
                const int col = wn * 64 + nt * 16 + li;
#pragma unroll
                for (int reg = 0; reg < 4; ++reg) {
                    const int row = m0 + wm * 32 + mt * 16 + quad * 4 + reg;
                    const float v = acc[mt][nt][reg] * sc;
                    hip_[(size_t)row * kH + col] = (unsigned short)(__float_as_uint(v) >> 16);
                    lop[(size_t)row * kH + col] =
                        (unsigned short)(__float_as_uint(v - hi_part(v)) >> 16);
                }
            }
    } else {
        // -------- v : single RNE-bf16 product --------
        for (int kt = 0; kt < kC; kt += 64) {
            if (kt) __syncthreads();
#pragma unroll
            for (int u = 0; u < 4; ++u) {
                const float4 xv =
                    *(const float4*)(x + (size_t)(m0 + ar) * kC + kt + ac + u * 4);
                unsigned short h0 = f2bf_rne(xv.x), h1 = f2bf_rne(xv.y);
                unsigned short h2 = f2bf_rne(xv.z), h3 = f2bf_rne(xv.w);
                *(uint2*)&Ah[ar][ac + u * 4] =
                    make_uint2(((unsigned)h1 << 16) | h0, ((unsigned)h3 << 16) | h2);
            }
#pragma unroll
            for (int u = 0; u < 4; ++u) {
                const int f = u * 256 + tid;
                const int row = f >> 3, g = (f & 7) ^ (row & 7);
                load_lds16(wThi + (size_t)row * kC + kt + g * 8, Bh + f * 8);
            }
            __syncthreads();

#pragma unroll
            for (int kc = 0; kc < 2; ++kc) {
                bf16x8 a[2];
#pragma unroll
                for (int mt = 0; mt < 2; ++mt)
                    a[mt] = *(const bf16x8*)&Ah[wm * 32 + mt * 16 + li][kc * 32 + quad * 8];
#pragma unroll
                for (int nt = 0; nt < 4; ++nt) {
                    const int row = wn * 64 + nt * 16 + li;
                    const int pos = (kc * 4 + quad) ^ (row & 7);
                    const bf16x8 bh = *(const bf16x8*)&Bh[row * 64 + pos * 8];
#pragma unroll
                    for (int mt = 0; mt < 2; ++mt)
                        acc[mt][nt] = __builtin_amdgcn_mfma_f32_16x16x32_bf16(a[mt], bh, acc[mt][nt], 0, 0, 0);
                }
            }
        }
        // epilogue: vT [B][H][T] bf16 RNE
        unsigned short* vt = ws + 4 * kMH;
        const int bb = m0 >> 11;
        const int t00 = (m0 & (kT - 1)) + wm * 32;
#pragma unroll
        for (int mt = 0; mt < 2; ++mt)
#pragma unroll
            for (int nt = 0; nt < 4; ++nt) {
                const int h = wn * 64 + nt * 16 + li;
                ushort4 pk;
                pk.x = f2bf_rne(acc[mt][nt][0]);
                pk.y = f2bf_rne(acc[mt][nt][1]);
                pk.z = f2bf_rne(acc[mt][nt][2]);
                pk.w = f2bf_rne(acc[mt][nt][3]);
                const int t0 = t00 + mt * 16 + quad * 4;
                *(ushort4*)&vt[((size_t)(bb * kH + h)) * kT + t0] = pk;
            }
    }
}

// ---------------------------------------------------------------------------
// Kernel 2: flash attention, barrier-free hot loop, low register pressure.
// 1024 blocks (b=idx&7, j=idx>>3 0..127) x 4 independent waves.
// Each block: 16 Q-rows; wave w handles 64-col K-chunks jc==w (mod 4).
// Q frags 32 VGPR, O 32 VGPR -> launch_bounds(256,4): 4 waves/SIMD.
// Softmax in exp2 domain (q pre-scaled by 32*log2e).
// qt = (j<64)? j : 191-j -> co-resident blocks {j, j+32, 127-j, 95-j}:
// per-CU chunk total constant (~67).
// ---------------------------------------------------------------------------
__global__ __launch_bounds__(256, 4) void attn_mfma(
    const unsigned short* __restrict__ ws, float* __restrict__ out)
{
    __shared__ __align__(16) unsigned short Ps[4][16][72];
    __shared__ __align__(16) float Ml[4][16][2];
    __shared__ __align__(16) float Obuf[3][16][132];

    const int tid = threadIdx.x;
    const int w = tid >> 6, lane = tid & 63;
    const int li = lane & 15, quad = lane >> 4;

    const int idx = blockIdx.x;
    const int b = idx & 7;
    const int j = idx >> 3;
    const int qt = (j < 64) ? j : 191 - j;
    const int i0 = qt * 16;
    const int nc = (qt + 4) >> 2;           // 64-col causal chunks

    const unsigned short* qhi = ws;
    const unsigned short* qlo = ws + kMH;
    const unsigned short* khi = ws + 2 * kMH;
    const unsigned short* klo = ws + 3 * kMH;
    const unsigned short* vt  = ws + 4 * kMH;

    // Q frags (A-layout), rows i0 + li
    bf16x8 qh[4], ql[4];
    {
        const size_t qoff = ((size_t)(b * kT + i0 + li)) * kH;
#pragma unroll
        for (int kc = 0; kc < 4; ++kc) {
            qh[kc] = *(const bf16x8*)(qhi + qoff + kc * 32 + quad * 8);
            ql[kc] = *(const bf16x8*)(qlo + qoff + kc * 32 + quad * 8);
        }
    }

    f32x4 o[8];
#pragma unroll
    for (int ht = 0; ht < 8; ++ht) o[ht] = (f32x4){0.f, 0.f, 0.f, 0.f};
    float m_i[4] = {-3.0e38f, -3.0e38f, -3.0e38f, -3.0e38f};
    float l_i[4] = {0.f, 0.f, 0.f, 0.f};

    for (int jc = w; jc < nc; jc += 4) {
        const int t0 = jc * 64;
        // ---- S = Q K^T (split-bf16), 64 cols ----
        f32x4 s[4];
#pragma unroll
        for (int nt = 0; nt < 4; ++nt) s[nt] = (f32x4){0.f, 0.f, 0.f, 0.f};
#pragma unroll
        for (int kc = 0; kc < 4; ++kc) {
#pragma unroll
            for (int nt = 0; nt < 4; ++nt) {
                const size_t ka =
                    ((size_t)(b * kT + t0 + nt * 16 + li)) * kH + kc * 32 + quad * 8;
                const bf16x8 kh = *(const bf16x8*)(khi + ka);
                const bf16x8 kl = *(const bf16x8*)(klo + ka);
                s[nt] = __builtin_amdgcn_mfma_f32_16x16x32_bf16(qh[kc], kh, s[nt], 0, 0, 0);
                s[nt] = __builtin_amdgcn_mfma_f32_16x16x32_bf16(ql[kc], kh, s[nt], 0, 0, 0);
                s[nt] = __builtin_amdgcn_mfma_f32_16x16x32_bf16(qh[kc], kl, s[nt], 0, 0, 0);
            }
        }
        // ---- causal mask (last chunk only; earlier chunks end <= diagonal) ----
        if (jc == nc - 1) {
            const int grow0 = i0 + quad * 4;
#pragma unroll
            for (int nt = 0; nt < 4; ++nt) {
                const int gcol = t0 + nt * 16 + li;
#pragma unroll
                for (int reg = 0; reg < 4; ++reg)
                    if (gcol > grow0 + reg) s[nt][reg] = -3.0e38f;
            }
        }
        // ---- online softmax (exp2 domain) ----
        float alpha[4];
#pragma unroll
        for (int reg = 0; reg < 4; ++reg) {
            float mr = fmaxf(fmaxf(s[0][reg], s[1][reg]), fmaxf(s[2][reg], s[3][reg]));
            mr = fmaxf(mr, __shfl_xor(mr, 1));
            mr = fmaxf(mr, __shfl_xor(mr, 2));
            mr = fmaxf(mr, __shfl_xor(mr, 4));
            mr = fmaxf(mr, __shfl_xor(mr, 8));
            const float mn = fmaxf(m_i[reg], mr);
            alpha[reg] = exp2f(m_i[reg] - mn);
            m_i[reg] = mn;
            float rs = 0.f;
#pragma unroll
            for (int nt = 0; nt < 4; ++nt) {
                const float p = exp2f(s[nt][reg] - mn);
                s[nt][reg] = p;
                rs += p;
            }
            rs += __shfl_xor(rs, 1);
            rs += __shfl_xor(rs, 2);
            rs += __shfl_xor(rs, 4);
            rs += __shfl_xor(rs, 8);
            l_i[reg] = l_i[reg] * alpha[reg] + rs;
        }
        const f32x4 av = {alpha[0], alpha[1], alpha[2], alpha[3]};
#pragma unroll
        for (int ht = 0; ht < 8; ++ht) o[ht] *= av;
        // ---- P -> per-wave LDS (C-layout) -> A-frags (same-wave ordering) ----
#pragma unroll
        for (int nt = 0; nt < 4; ++nt)
#pragma unroll
            for (int reg = 0; reg < 4; ++reg)
                Ps[w][quad * 4 + reg][nt * 16 + li] = f2bf_rne(s[nt][reg]);
        const bf16x8 pf0 = *(const bf16x8*)&Ps[w][li][quad * 8];
        const bf16x8 pf1 = *(const bf16x8*)&Ps[w][li][32 + quad * 8];
        // ---- O += P V (V B-frags straight from global) ----
#pragma unroll
        for (int ht = 0; ht < 8; ++ht) {
            const size_t va = (size_t)(b * kH + ht * 16 + li) * kT + t0;
            const bf16x8 v0 = *(const bf16x8*)(vt + va + quad * 8);
            const bf16x8 v1 = *(const bf16x8*)(vt + va + 32 + quad * 8);
            o[ht] = __builtin_amdgcn_mfma_f32_16x16x32_bf16(pf0, v0, o[ht], 0, 0, 0);
            o[ht] = __builtin_amdgcn_mfma_f32_16x16x32_bf16(pf1, v1, o[ht], 0, 0, 0);
        }
    }

    // ---- 4-way merge across waves ----
    if (li == 0) {
#pragma unroll
        for (int reg = 0; reg < 4; ++reg) {
            Ml[w][quad * 4 + reg][0] = m_i[reg];
            Ml[w][quad * 4 + reg][1] = l_i[reg];
        }
    }
    __syncthreads();
    float a_self[4], linv[4];
#pragma unroll
    for (int reg = 0; reg < 4; ++reg) {
        const int row = quad * 4 + reg;
        const float m0_ = Ml[0][row][0], m1 = Ml[1][row][0];
        const float m2 = Ml[2][row][0], m3 = Ml[3][row][0];
        const float ms = fmaxf(fmaxf(m0_, m1), fmaxf(m2, m3));
        const float L = Ml[0][row][1] * exp2f(m0_ - ms) +
                        Ml[1][row][1] * exp2f(m1 - ms) +
                        Ml[2][row][1] * exp2f(m2 - ms) +
                        Ml[3][row][1] * exp2f(m3 - ms);
        a_self[reg] = exp2f(m_i[reg] - ms);
        linv[reg] = 1.0f / L;
    }
    if (w) {
#pragma unroll
        for (int ht = 0; ht < 8; ++ht)
#pragma unroll
            for (int reg = 0; reg < 4; ++reg)
                Obuf[w - 1][quad * 4 + reg][ht * 16 + li] =
                    o[ht][reg] * a_self[reg];
    }
    __syncthreads();
    if (w == 0) {
#pragma unroll
        for (int ht = 0; ht < 8; ++ht)
#pragma unroll
            for (int reg = 0; reg < 4; ++reg) {
                const int row = quad * 4 + reg;
                const int col = ht * 16 + li;
                const float v = o[ht][reg] * a_self[reg] +
                                Obuf[0][row][col] + Obuf[1][row][col] +
                                Obuf[2][row][col];
                out[(size_t)(b * kT + i0 + row) * kH + col] = v * linv[reg];
            }
    }
}

// ---------------------------------------------------------------------------
extern "C" void kernel_launch(void* const* d_in, const int* in_sizes, int n_in,
                              void* d_out, int out_size, void* d_ws, size_t ws_size,
                              hipStream_t stream) {
    // setup_inputs order: x, Wk, Wq, Wv
    const float* x  = (const float*)d_in[0];
    const float* Wk = (const float*)d_in[1];
    const float* Wq = (const float*)d_in[2];
    const float* Wv = (const float*)d_in[3];
    unsigned short* ws = (unsigned short*)d_ws;
    float* out = (float*)d_out;

    hipLaunchKernelGGL(prep_w, dim3(128, 3), dim3(256), 0, stream, Wk, Wq, Wv, ws);
    hipLaunchKernelGGL(qkv_mfma, dim3(768), dim3(256), 0, stream, x, ws);
    hipLaunchKernelGGL(attn_mfma, dim3(1024), dim3(256), 0, stream,
                       (const unsigned short*)ws, out);
}

// Round 7
// 195.464 us; speedup vs baseline: 1.1751x; 1.1751x over previous
//
#include <hip/hip_runtime.h>

// Problem constants: B=8, T=2048, C=1024, H=128
constexpr int kB = 8;
constexpr int kT = 2048;
constexpr int kC = 1024;
constexpr int kH = 128;
constexpr int kM = kB * kT;                 // 16384 rows
constexpr size_t kMH = (size_t)kM * kH;     // 2,097,152
constexpr size_t kWH = (size_t)kC * kH;     // 131,072

// q is pre-scaled by sqrt(C)*log2(e) so softmax can use exp2 directly.
#define QSCALE 46.166241308446828f          // 32 * 1.4426950408889634

typedef __attribute__((ext_vector_type(8))) short bf16x8;   // MFMA A/B frag
typedef __attribute__((ext_vector_type(4))) float f32x4;    // MFMA C/D frag

// ws layout (ushort): qhi | qlo | khi | klo | vT[B][H][T] | 6x WT (hi/lo per mat)

__device__ inline unsigned short f2bf_rne(float f) {
    union { float f; unsigned int u; } x; x.f = f;
    unsigned int r = x.u + 0x7fff + ((x.u >> 16) & 1);
    return (unsigned short)(r >> 16);
}
__device__ inline float bf2f(unsigned short h) {
    union { float f; unsigned int u; } x; x.u = ((unsigned int)h) << 16;
    return x.f;
}
__device__ inline unsigned int pack_hi2(float a, float b) {  // trunc-hi16 pack
    return __builtin_amdgcn_perm(__float_as_uint(b), __float_as_uint(a),
                                 0x07060302u);
}
__device__ inline float hi_part(float v) {
    return __uint_as_float(__float_as_uint(v) & 0xffff0000u);
}
__device__ inline void load_lds16(const unsigned short* g, unsigned short* l) {
    __builtin_amdgcn_global_load_lds(
        (const __attribute__((address_space(1))) unsigned int*)g,
        (__attribute__((address_space(3))) unsigned int*)l, 16, 0, 0);
}

// ---------------------------------------------------------------------------
// Kernel 0: split + transpose weights -> WT_hi (RNE) / WT_lo [H][C] bf16.
// ---------------------------------------------------------------------------
__global__ __launch_bounds__(256) void prep_w(
    const float* __restrict__ Wk, const float* __restrict__ Wq,
    const float* __restrict__ Wv, unsigned short* __restrict__ ws)
{
    const int h = blockIdx.x;
    const int mat = blockIdx.y;
    const float* W = (mat == 0) ? Wq : (mat == 1) ? Wk : Wv;
    unsigned short* hi = ws + 5 * kMH + (size_t)(mat * 2) * kWH;
    unsigned short* lo = hi + kWH;

    const int k0 = threadIdx.x * 4;
    unsigned short hv[4], lv[4];
#pragma unroll
    for (int j = 0; j < 4; ++j) {
        const float f = W[(size_t)(k0 + j) * kH + h];
        hv[j] = f2bf_rne(f);
        lv[j] = f2bf_rne(f - bf2f(hv[j]));
    }
    *(uint2*)&hi[(size_t)h * kC + k0] =
        make_uint2(((unsigned)hv[1] << 16) | hv[0], ((unsigned)hv[3] << 16) | hv[2]);
    *(uint2*)&lo[(size_t)h * kC + k0] =
        make_uint2(((unsigned)lv[1] << 16) | lv[0], ((unsigned)lv[3] << 16) | lv[2]);
}

// ---------------------------------------------------------------------------
// Kernel 1: QKV projection, A-in-register design.
// 768 blocks: idx<256 q | <512 k | <768 v.  M-tile 64 rows; block = 4 waves;
// wave w handles rows m0+w*16.. (one 16-row m-frag) x all 128 cols.
// A-frags built IN-REGISTER from global x (8 contiguous fp32/lane -> hi/lo
// pack) -- no A LDS, no A barrier. Only B (WT hi/lo, [128][64] bf16, 32 KB)
// staged per K-step via swizzled global_load_lds.
// CU c hosts the (q,k,v) triple for the same m0 -> x rows L2-hot.
// ---------------------------------------------------------------------------
__global__ __launch_bounds__(256) void qkv_mfma(
    const float* __restrict__ x, unsigned short* __restrict__ ws)
{
    __shared__ __align__(16) unsigned short Bh[128 * 64];
    __shared__ __align__(16) unsigned short Bl[128 * 64];

    const int idx = blockIdx.x;
    const int mat = idx >> 8;               // 0=q, 1=k, 2=v
    const int m0 = (idx & 255) * 64;
    const unsigned short* wThi = ws + 5 * kMH + (size_t)(mat * 2) * kWH;
    const unsigned short* wTlo = wThi + kWH;

    const int tid = threadIdx.x;
    const int w = tid >> 6, lane = tid & 63;
    const int li = lane & 15, quad = lane >> 4;

    const float* xrow = x + (size_t)(m0 + w * 16 + li) * kC;

    f32x4 acc[8];
#pragma unroll
    for (int j = 0; j < 8; ++j) acc[j] = (f32x4){0.f, 0.f, 0.f, 0.f};

    for (int kt = 0; kt < kC; kt += 64) {
        if (kt) __syncthreads();
        // ---- stage B [128 rows][64 cols] hi(+lo) via swizzled DMA ----
#pragma unroll
        for (int u = 0; u < 4; ++u) {
            const int f = u * 256 + tid;
            const int row = f >> 3, g = (f & 7) ^ (row & 7);
            load_lds16(wThi + (size_t)row * kC + kt + g * 8, Bh + f * 8);
            if (mat <= 1)
                load_lds16(wTlo + (size_t)row * kC + kt + g * 8, Bl + f * 8);
        }
        // ---- A-frags in-register from global x ----
        float4 xa[2][2];
#pragma unroll
        for (int kc = 0; kc < 2; ++kc) {
            xa[kc][0] = *(const float4*)(xrow + kt + kc * 32 + quad * 8);
            xa[kc][1] = *(const float4*)(xrow + kt + kc * 32 + quad * 8 + 4);
        }
        bf16x8 ah[2], al[2];
        if (mat <= 1) {
#pragma unroll
            for (int kc = 0; kc < 2; ++kc) {
                const float4 a0 = xa[kc][0], a1 = xa[kc][1];
                unsigned int hp[4], lp[4];
                hp[0] = pack_hi2(a0.x, a0.y); hp[1] = pack_hi2(a0.z, a0.w);
                hp[2] = pack_hi2(a1.x, a1.y); hp[3] = pack_hi2(a1.z, a1.w);
                lp[0] = pack_hi2(a0.x - hi_part(a0.x), a0.y - hi_part(a0.y));
                lp[1] = pack_hi2(a0.z - hi_part(a0.z), a0.w - hi_part(a0.w));
                lp[2] = pack_hi2(a1.x - hi_part(a1.x), a1.y - hi_part(a1.y));
                lp[3] = pack_hi2(a1.z - hi_part(a1.z), a1.w - hi_part(a1.w));
                ah[kc] = *(bf16x8*)hp;
                al[kc] = *(bf16x8*)lp;
            }
        } else {
#pragma unroll
            for (int kc = 0; kc < 2; ++kc) {
                const float4 a0 = xa[kc][0], a1 = xa[kc][1];
                unsigned short e[8];
                e[0] = f2bf_rne(a0.x); e[1] = f2bf_rne(a0.y);
                e[2] = f2bf_rne(a0.z); e[3] = f2bf_rne(a0.w);
                e[4] = f2bf_rne(a1.x); e[5] = f2bf_rne(a1.y);
                e[6] = f2bf_rne(a1.z); e[7] = f2bf_rne(a1.w);
                ah[kc] = *(bf16x8*)e;
            }
        }
        __syncthreads();

        // ---- MFMA over all 128 cols ----
        if (mat <= 1) {
#pragma unroll
            for (int kc = 0; kc < 2; ++kc)
#pragma unroll
                for (int nt = 0; nt < 8; ++nt) {
                    const int row = nt * 16 + li;
                    const int pos = (kc * 4 + quad) ^ (row & 7);
                    const bf16x8 bh = *(const bf16x8*)&Bh[row * 64 + pos * 8];
                    const bf16x8 bl = *(const bf16x8*)&Bl[row * 64 + pos * 8];
                    acc[nt] = __builtin_amdgcn_mfma_f32_16x16x32_bf16(ah[kc], bh, acc[nt], 0, 0, 0);
                    acc[nt] = __builtin_amdgcn_mfma_f32_16x16x32_bf16(al[kc], bh, acc[nt], 0, 0, 0);
                    acc[nt] = __builtin_amdgcn_mfma_f32_16x16x32_bf16(ah[kc], bl, acc[nt], 0, 0, 0);
                }
        } else {
#pragma unroll
            for (int kc = 0; kc < 2; ++kc)
#pragma unroll
                for (int nt = 0; nt < 8; ++nt) {
                    const int row = nt * 16 + li;
                    const int pos = (kc * 4 + quad) ^ (row & 7);
                    const bf16x8 bh = *(const bf16x8*)&Bh[row * 64 + pos * 8];
                    acc[nt] = __builtin_amdgcn_mfma_f32_16x16x32_bf16(ah[kc], bh, acc[nt], 0, 0, 0);
                }
        }
    }

    // ---- epilogue ----
    if (mat <= 1) {
        unsigned short* hip_ = ws + (size_t)(mat * 2) * kMH;
        unsigned short* lop  = hip_ + kMH;
        const float sc = (mat == 0) ? QSCALE : 1.0f;
#pragma unroll
        for (int nt = 0; nt < 8; ++nt) {
            const int col = nt * 16 + li;
#pragma unroll
            for (int reg = 0; reg < 4; ++reg) {
                const int row = m0 + w * 16 + quad * 4 + reg;
                const float v = acc[nt][reg] * sc;
                hip_[(size_t)row * kH + col] = (unsigned short)(__float_as_uint(v) >> 16);
                lop[(size_t)row * kH + col] =
                    (unsigned short)(__float_as_uint(v - hi_part(v)) >> 16);
            }
        }
    } else {
        unsigned short* vt = ws + 4 * kMH;
        const int bb = m0 >> 11;
        const int t0 = (m0 & (kT - 1)) + w * 16 + quad * 4;
#pragma unroll
        for (int nt = 0; nt < 8; ++nt) {
            const int h = nt * 16 + li;
            ushort4 pk;
            pk.x = f2bf_rne(acc[nt][0]);
            pk.y = f2bf_rne(acc[nt][1]);
            pk.z = f2bf_rne(acc[nt][2]);
            pk.w = f2bf_rne(acc[nt][3]);
            *(ushort4*)&vt[((size_t)(bb * kH + h)) * kT + t0] = pk;
        }
    }
}

// ---------------------------------------------------------------------------
// Kernel 2: flash attention, barrier-free hot loop (R5 structure, exp2).
// 512 blocks (b=idx&7 -> XCD-local K/V in L2) x 4 INDEPENDENT waves.
// Wave w: all 32 Q-rows (2 m-frags), K-chunks jc == w (mod 4), 32 cols each.
// K/V B-frags read DIRECTLY from global (contiguous 16B/lane, L2-resident).
// Private online softmax per wave; 4-way (m,l,O) merge once at the end.
// ---------------------------------------------------------------------------
__global__ __launch_bounds__(256, 2) void attn_mfma(
    const unsigned short* __restrict__ ws, float* __restrict__ out)
{
    __shared__ __align__(16) unsigned short Ps[4][2][16][40];
    __shared__ __align__(16) float Ml[4][32][2];
    __shared__ __align__(16) float Obuf[3][32][128];

    const int tid = threadIdx.x;
    const int w = tid >> 6, lane = tid & 63;
    const int li = lane & 15, quad = lane >> 4;

    const int idx = blockIdx.x;
    const int b = idx & 7;
    const int j = idx >> 3;
    const int qt = (j < 32) ? j : 95 - j;   // pair qt with 63-qt per CU
    const int i0 = qt * 32;
    const int nc = qt + 1;                  // 32-col causal chunks

    const unsigned short* qhi = ws;
    const unsigned short* qlo = ws + kMH;
    const unsigned short* khi = ws + 2 * kMH;
    const unsigned short* klo = ws + 3 * kMH;
    const unsigned short* vt  = ws + 4 * kMH;

    // Q frags (A-layout), 2 m-tiles
    bf16x8 qh[2][4], ql[2][4];
#pragma unroll
    for (int mi = 0; mi < 2; ++mi) {
        const size_t qoff = ((size_t)(b * kT + i0 + mi * 16 + li)) * kH;
#pragma unroll
        for (int kc = 0; kc < 4; ++kc) {
            qh[mi][kc] = *(const bf16x8*)(qhi + qoff + kc * 32 + quad * 8);
            ql[mi][kc] = *(const bf16x8*)(qlo + qoff + kc * 32 + quad * 8);
        }
    }

    f32x4 o[2][8];
#pragma unroll
    for (int mi = 0; mi < 2; ++mi)
#pragma unroll
        for (int ht = 0; ht < 8; ++ht) o[mi][ht] = (f32x4){0.f, 0.f, 0.f, 0.f};
    float m_i[2][4], l_i[2][4];
#pragma unroll
    for (int mi = 0; mi < 2; ++mi)
#pragma unroll
        for (int reg = 0; reg < 4; ++reg) { m_i[mi][reg] = -3.0e38f; l_i[mi][reg] = 0.f; }

    for (int jc = w; jc < nc; jc += 4) {
        const int t0 = jc * 32;
        // V B-frags (used at the end -> latency covered by QK+softmax)
        bf16x8 vf[8];
#pragma unroll
        for (int ht = 0; ht < 8; ++ht)
            vf[ht] = *(const bf16x8*)(vt + (size_t)(b * kH + ht * 16 + li) * kT +
                                      t0 + quad * 8);
        // S = Q K^T (split-bf16)
        f32x4 s[2][2];
#pragma unroll
        for (int mi = 0; mi < 2; ++mi)
#pragma unroll
            for (int nt = 0; nt < 2; ++nt) s[mi][nt] = (f32x4){0.f, 0.f, 0.f, 0.f};
#pragma unroll
        for (int kc = 0; kc < 4; ++kc) {
            bf16x8 kh[2], kl[2];
#pragma unroll
            for (int nt = 0; nt < 2; ++nt) {
                const size_t ka =
                    ((size_t)(b * kT + t0 + nt * 16 + li)) * kH + kc * 32 + quad * 8;
                kh[nt] = *(const bf16x8*)(khi + ka);
                kl[nt] = *(const bf16x8*)(klo + ka);
            }
#pragma unroll
            for (int mi = 0; mi < 2; ++mi)
#pragma unroll
                for (int nt = 0; nt < 2; ++nt) {
                    s[mi][nt] = __builtin_amdgcn_mfma_f32_16x16x32_bf16(qh[mi][kc], kh[nt], s[mi][nt], 0, 0, 0);
                    s[mi][nt] = __builtin_amdgcn_mfma_f32_16x16x32_bf16(ql[mi][kc], kh[nt], s[mi][nt], 0, 0, 0);
                    s[mi][nt] = __builtin_amdgcn_mfma_f32_16x16x32_bf16(qh[mi][kc], kl[nt], s[mi][nt], 0, 0, 0);
                }
        }
        // causal mask (diagonal chunk only)
        if (jc == qt) {
#pragma unroll
            for (int mi = 0; mi < 2; ++mi) {
                const int grow0 = i0 + mi * 16 + quad * 4;
#pragma unroll
                for (int nt = 0; nt < 2; ++nt) {
                    const int gcol = t0 + nt * 16 + li;
#pragma unroll
                    for (int reg = 0; reg < 4; ++reg)
                        if (gcol > grow0 + reg) s[mi][nt][reg] = -3.0e38f;
                }
            }
        }
        // online softmax (exp2 domain)
#pragma unroll
        for (int mi = 0; mi < 2; ++mi) {
            float alpha[4];
#pragma unroll
            for (int reg = 0; reg < 4; ++reg) {
                float mr = fmaxf(s[mi][0][reg], s[mi][1][reg]);
                mr = fmaxf(mr, __shfl_xor(mr, 1));
                mr = fmaxf(mr, __shfl_xor(mr, 2));
                mr = fmaxf(mr, __shfl_xor(mr, 4));
                mr = fmaxf(mr, __shfl_xor(mr, 8));
                const float mn = fmaxf(m_i[mi][reg], mr);
                alpha[reg] = exp2f(m_i[mi][reg] - mn);
                m_i[mi][reg] = mn;
                const float p0 = exp2f(s[mi][0][reg] - mn);
                const float p1 = exp2f(s[mi][1][reg] - mn);
                s[mi][0][reg] = p0; s[mi][1][reg] = p1;
                float rs = p0 + p1;
                rs += __shfl_xor(rs, 1);
                rs += __shfl_xor(rs, 2);
                rs += __shfl_xor(rs, 4);
                rs += __shfl_xor(rs, 8);
                l_i[mi][reg] = l_i[mi][reg] * alpha[reg] + rs;
            }
            const f32x4 av = {alpha[0], alpha[1], alpha[2], alpha[3]};
#pragma unroll
            for (int ht = 0; ht < 8; ++ht) o[mi][ht] *= av;
            // P -> per-wave LDS (C-layout) -> A-frag (same-wave, no barrier)
#pragma unroll
            for (int nt = 0; nt < 2; ++nt)
#pragma unroll
                for (int reg = 0; reg < 4; ++reg)
                    Ps[w][mi][quad * 4 + reg][nt * 16 + li] = f2bf_rne(s[mi][nt][reg]);
        }
#pragma unroll
        for (int mi = 0; mi < 2; ++mi) {
            const bf16x8 pf = *(const bf16x8*)&Ps[w][mi][li][quad * 8];
#pragma unroll
            for (int ht = 0; ht < 8; ++ht)
                o[mi][ht] = __builtin_amdgcn_mfma_f32_16x16x32_bf16(pf, vf[ht], o[mi][ht], 0, 0, 0);
        }
    }

    // ---- 4-way merge across waves ----
    if (li == 0) {
#pragma unroll
        for (int mi = 0; mi < 2; ++mi)
#pragma unroll
            for (int reg = 0; reg < 4; ++reg) {
                Ml[w][mi * 16 + quad * 4 + reg][0] = m_i[mi][reg];
                Ml[w][mi * 16 + quad * 4 + reg][1] = l_i[mi][reg];
            }
    }
    __syncthreads();
    float a_self[2][4], linv[2][4];
#pragma unroll
    for (int mi = 0; mi < 2; ++mi)
#pragma unroll
        for (int reg = 0; reg < 4; ++reg) {
            const int row = mi * 16 + quad * 4 + reg;
            const float m0_ = Ml[0][row][0], m1 = Ml[1][row][0];
            const float m2 = Ml[2][row][0], m3 = Ml[3][row][0];
            const float ms = fmaxf(fmaxf(m0_, m1), fmaxf(m2, m3));
            const float L = Ml[0][row][1] * exp2f(m0_ - ms) +
                            Ml[1][row][1] * exp2f(m1 - ms) +
                            Ml[2][row][1] * exp2f(m2 - ms) +
                            Ml[3][row][1] * exp2f(m3 - ms);
            a_self[mi][reg] = exp2f(m_i[mi][reg] - ms);
            linv[mi][reg] = 1.0f / L;
        }
    if (w) {
#pragma unroll
        for (int mi = 0; mi < 2; ++mi)
#pragma unroll
            for (int ht = 0; ht < 8; ++ht)
#pragma unroll
                for (int reg = 0; reg < 4; ++reg)
                    Obuf[w - 1][mi * 16 + quad * 4 + reg][ht * 16 + li] =
                        o[mi][ht][reg] * a_self[mi][reg];
    }
    __syncthreads();
    if (w == 0) {
#pragma unroll
        for (int mi = 0; mi < 2; ++mi)
#pragma unroll
            for (int ht = 0; ht < 8; ++ht)
#pragma unroll
                for (int reg = 0; reg < 4; ++reg) {
                    const int row = mi * 16 + quad * 4 + reg;
                    const int col = ht * 16 + li;
                    const float v = o[mi][ht][reg] * a_self[mi][reg] +
                                    Obuf[0][row][col] + Obuf[1][row][col] +
                                    Obuf[2][row][col];
                    out[(size_t)(b * kT + i0 + row) * kH + col] = v * linv[mi][reg];
                }
    }
}

// ---------------------------------------------------------------------------
extern "C" void kernel_launch(void* const* d_in, const int* in_sizes, int n_in,
                              void* d_out, int out_size, void* d_ws, size_t ws_size,
                              hipStream_t stream) {
    // setup_inputs order: x, Wk, Wq, Wv
    const float* x  = (const float*)d_in[0];
    const float* Wk = (const float*)d_in[1];
    const float* Wq = (const float*)d_in[2];
    const float* Wv = (const float*)d_in[3];
    unsigned short* ws = (unsigned short*)d_ws;
    float* out = (float*)d_out;

    hipLaunchKernelGGL(prep_w, dim3(128, 3), dim3(256), 0, stream, Wk, Wq, Wv, ws);
    hipLaunchKernelGGL(qkv_mfma, dim3(768), dim3(256), 0, stream, x, ws);
    hipLaunchKernelGGL(attn_mfma, dim3(512), dim3(256), 0, stream,
                       (const unsigned short*)ws, out);
}